// Round 4
// baseline (219.494 us; speedup 1.0000x reference)
//
#include <hip/hip_runtime.h>

#define NN 10000
#define NCAND 201
#define NB 64

typedef __attribute__((ext_vector_type(8))) short short8;
typedef __attribute__((ext_vector_type(4))) float f32x4;

__device__ __forceinline__ float bf2f(unsigned short u) {
  return __uint_as_float(((unsigned int)u) << 16);
}
__device__ __forceinline__ unsigned short f2bf(float f) {
  unsigned int u = __float_as_uint(f);
  u += 0x7FFFu + ((u >> 16) & 1u);   // RNE
  return (unsigned short)(u >> 16);
}
__device__ __forceinline__ float fast_tanh(float x) {
  return 1.0f - 2.0f / (__expf(2.0f * x) + 1.0f);
}
// generic load: flag=1 -> float32 array, flag=0 -> bf16 array
__device__ __forceinline__ float gld(const void* p, long i, int f) {
  return f ? ((const float*)p)[i] : bf2f(((const unsigned short*)p)[i]);
}

// ---------------------------------------------------------------------------
// MEGA launch:
//  [0,1024)    : feat_pool role -- partial pooling into psumP/pmaxP. R19: the
//                16th finisher of each batch (fpcnt counter, memset-zeroed
//                pre-launch) runs a TAIL computing pact[b] + critic v[b] once
//                per batch. Tail latency overlaps remaining mega blocks --
//                off actorB's critical path (R1-R3 showed per-actor-block
//                pooled work costs ~+14us regardless of implementation).
//                G16: tail reads psum/pmax via device-scope atomic reads;
//                producers: plain stores + syncthreads + t0 threadfence +
//                device atomicAdd on fpcnt (same pattern as actorB softmax).
//  [1024,1472) : actorA role -- candidate h1 -> layer2 features cf -> cfw.
//  [1472,1856) : transpose aw1t/aw2t (cw1t/cw2t dropped: critic reads
//                original k-major weights in the tail, coalesced).
//  [1856,1873) : F[j] flags. 1873: mask mode. 1874: cand width + zero scnt.
// ---------------------------------------------------------------------------
__global__ __launch_bounds__(256, 4)
void mega_kernel(const void* __restrict__ x, const int* __restrict__ cand,
                 const void* w1, const void* b1, const void* w2, const void* b2,
                 const void* aw1, const void* ab1, const void* aw2, const void* ab2,
                 const void* aw3, const void* ab3,
                 const void* cw1, const void* cb1, const void* cw2, const void* cb2,
                 const void* cw3, const void* cb3,
                 const unsigned int* mask_w, const unsigned int* cand_w,
                 int* F, int* scnt, int* fpcnt,
                 float* __restrict__ psumP, float* __restrict__ pmaxP,
                 float* __restrict__ pact, float* __restrict__ vws,
                 unsigned short* __restrict__ cfw,
                 unsigned short* __restrict__ aw1t, unsigned short* __restrict__ aw2t) {
  __shared__ __align__(16) unsigned short pool[128 * 72];  // 18432 B overlay
  __shared__ float w1f[3 * 64];
  __shared__ float b1f[64];
  __shared__ float b2f[128];
  __shared__ int cnts[8];

  const int t = threadIdx.x;
  const int j = blockIdx.x;
  const int lane = t & 63;
  const int wv = t >> 6;

  if (j < 1472) {
    // ---- shared self-detect for fp/actorA roles: x,w1,b1,b2,w2,cand ----
    if (t < 8) cnts[t] = 0;
    __syncthreads();
    {
      if ((((const unsigned short*)x)[t] & 0x7F80u) >= 0x4300u) atomicAdd(&cnts[0], 1);
      if (t < 192 && (((const unsigned short*)w1)[t] & 0x7F80u) >= 0x4300u) atomicAdd(&cnts[1], 1);
      if (t < 64 && (((const unsigned short*)b1)[t] & 0x7F80u) >= 0x4300u) atomicAdd(&cnts[2], 1);
      if (t < 128 && (((const unsigned short*)b2)[t] & 0x7F80u) >= 0x4300u) atomicAdd(&cnts[3], 1);
      if ((((const unsigned short*)w2)[t] & 0x7F80u) >= 0x4300u) atomicAdd(&cnts[4], 1);
      int co = 0;
#pragma unroll
      for (int q = 0; q < 4; ++q) {
        int i = t * 4 + q;
        if ((i & 1) && cand_w[i] != 0u) co = 1;
      }
      if (co) atomicAdd(&cnts[5], 1);
    }
    __syncthreads();
    const int F0 = cnts[0] > 32, F1 = cnts[1] > 24, F2 = cnts[2] > 8;
    const int F4 = cnts[3] > 16, Fw2 = cnts[4] > 32, C64 = cnts[5] == 0;

    if (j < 1024) {
      // ================= feat_pool role =================
      unsigned short* h1s = pool;  // [128][72]
      const int b = j >> 4;
      const int s = j & 15;

      if (t < 192) w1f[t] = gld(w1, t, F1);
      if (t < 64) b1f[t] = gld(b1, t, F2);
      if (t < 128) b2f[t] = gld(b2, t, F4);

      // B fragments gathered from fe_w2 [k][n] (strided scalar, once/block)
      short8 bfr[2][2];
#pragma unroll
      for (int nl = 0; nl < 2; ++nl)
#pragma unroll
        for (int ks = 0; ks < 2; ++ks) {
          int col = wv * 32 + nl * 16 + (lane & 15);
          short8 v;
#pragma unroll
          for (int jj = 0; jj < 8; ++jj) {
            int k = (lane >> 4) * 8 + ks * 32 + jj;
            v[jj] = (short)f2bf(gld(w2, (long)k * 128 + col, Fw2));
          }
          bfr[nl][ks] = v;
        }
      __syncthreads();

      float csum[2] = {0.f, 0.f};
      float cmax[2] = {0.f, 0.f};
      const int m = t & 127;
      const int kg = t >> 7;

      float x0 = 0.f, x1 = 0.f, x2 = 0.f;
      if (s < 79) {
        int nb = s * 128;
        if (m < min(128, NN - nb)) {
          long xo = ((long)b * NN + nb + m) * 3;
          x0 = gld(x, xo, F0); x1 = gld(x, xo + 1, F0); x2 = gld(x, xo + 2, F0);
        }
      }

      for (int c = s; c < 79; c += 16) {
        int nb = c * 128;
        int cnt = (nb + 128 <= NN) ? 128 : (NN - nb);
        const bool full = (cnt == 128);  // uniform across block
        if (full) {
#pragma unroll
          for (int blk = 0; blk < 4; ++blk) {
            short8 v;
#pragma unroll
            for (int i = 0; i < 8; ++i) {
              int k = kg * 32 + blk * 8 + i;
              float vv = x0 * w1f[k] + x1 * w1f[64 + k] + x2 * w1f[128 + k] + b1f[k];
              v[i] = (short)f2bf(fmaxf(vv, 0.f));
            }
            *(short8*)(h1s + m * 72 + kg * 32 + blk * 8) = v;
          }
        } else if (m < cnt) {
#pragma unroll
          for (int blk = 0; blk < 4; ++blk) {
            short8 v;
#pragma unroll
            for (int i = 0; i < 8; ++i) {
              int k = kg * 32 + blk * 8 + i;
              float vv = x0 * w1f[k] + x1 * w1f[64 + k] + x2 * w1f[128 + k] + b1f[k];
              v[i] = (short)f2bf(fmaxf(vv, 0.f));
            }
            *(short8*)(h1s + m * 72 + kg * 32 + blk * 8) = v;
          }
        }
        {
          int cn = c + 16;
          float nx0 = 0.f, nx1 = 0.f, nx2 = 0.f;
          if (cn < 79) {
            int nbn = cn * 128;
            if (m < min(128, NN - nbn)) {
              long xo = ((long)b * NN + nbn + m) * 3;
              nx0 = gld(x, xo, F0); nx1 = gld(x, xo + 1, F0); nx2 = gld(x, xo + 2, F0);
            }
          }
          __syncthreads();
          x0 = nx0; x1 = nx1; x2 = nx2;
        }
        if (full) {
          // unchecked epilogue (all rows valid)
#pragma unroll
          for (int mt = 0; mt < 8; ++mt) {
            const unsigned short* ap = h1s + (mt * 16 + (lane & 15)) * 72 + ((lane >> 4) * 8);
            short8 af0 = *(const short8*)(ap);
            short8 af1 = *(const short8*)(ap + 32);
#pragma unroll
            for (int nl = 0; nl < 2; ++nl) {
              f32x4 acc = {0.f, 0.f, 0.f, 0.f};
              acc = __builtin_amdgcn_mfma_f32_16x16x32_bf16(af0, bfr[nl][0], acc, 0, 0, 0);
              acc = __builtin_amdgcn_mfma_f32_16x16x32_bf16(af1, bfr[nl][1], acc, 0, 0, 0);
              int col = wv * 32 + nl * 16 + (lane & 15);
              float bb = b2f[col];
#pragma unroll
              for (int r = 0; r < 4; ++r) {
                float v = fmaxf(acc[r] + bb, 0.f);
                csum[nl] += v;
                cmax[nl] = fmaxf(cmax[nl], v);
              }
            }
          }
        } else {
#pragma unroll
          for (int mt = 0; mt < 8; ++mt) {
            const unsigned short* ap = h1s + (mt * 16 + (lane & 15)) * 72 + ((lane >> 4) * 8);
            short8 af0 = *(const short8*)(ap);
            short8 af1 = *(const short8*)(ap + 32);
#pragma unroll
            for (int nl = 0; nl < 2; ++nl) {
              f32x4 acc = {0.f, 0.f, 0.f, 0.f};
              acc = __builtin_amdgcn_mfma_f32_16x16x32_bf16(af0, bfr[nl][0], acc, 0, 0, 0);
              acc = __builtin_amdgcn_mfma_f32_16x16x32_bf16(af1, bfr[nl][1], acc, 0, 0, 0);
              int col = wv * 32 + nl * 16 + (lane & 15);
              float bb = b2f[col];
#pragma unroll
              for (int r = 0; r < 4; ++r) {
                int row = mt * 16 + ((lane >> 4) * 4) + r;
                if (row < cnt) {
                  float v = fmaxf(acc[r] + bb, 0.f);
                  csum[nl] += v;
                  cmax[nl] = fmaxf(cmax[nl], v);
                }
              }
            }
          }
        }
        __syncthreads();
      }
#pragma unroll
      for (int nl = 0; nl < 2; ++nl) {
        csum[nl] += __shfl_xor(csum[nl], 16);
        csum[nl] += __shfl_xor(csum[nl], 32);
        cmax[nl] = fmaxf(cmax[nl], __shfl_xor(cmax[nl], 16));
        cmax[nl] = fmaxf(cmax[nl], __shfl_xor(cmax[nl], 32));
      }
      if (lane < 16) {
#pragma unroll
        for (int nl = 0; nl < 2; ++nl) {
          int col = wv * 32 + nl * 16 + lane;
          psumP[((long)b * 16 + s) * 128 + col] = csum[nl];   // plain stores
          pmaxP[((long)b * 16 + s) * 128 + col] = cmax[nl];
        }
      }

      // ---- R19 tail: 16th finisher of batch b computes pact + critic ----
      __syncthreads();   // all waves' psum/pmax stores retired to L2
      if (t == 0) {
        __threadfence();  // L2 writeback: stores device-visible before count
        cnts[7] = (atomicAdd(&fpcnt[b], 1) == 15) ? 1 : 0;
      }
      __syncthreads();
      if (!cnts[7]) return;

      {
        float* plfF = (float*)pool;        // [256] raw pooled (critic)
        float* plfQ = plfF + 256;          // [256] bf16-quantized (actor)
        float* c1s  = plfF + 512;          // [256] critic h1
        float* redt = plfF + 768;          // [4]

        // self-detect flags for tail arrays (housekeeping formula: K, >K>>3)
        if (t < 8) cnts[t] = 0;
        __syncthreads();
        {
          int c5 = 0, c11 = 0, c13 = 0;
          for (int i = t; i < 2048; i += 256) {
            if ((((const unsigned short*)aw1)[i] & 0x7F80u) >= 0x4300u) c5++;
            if ((((const unsigned short*)cw1)[i] & 0x7F80u) >= 0x4300u) c11++;
            if ((((const unsigned short*)cw2)[i] & 0x7F80u) >= 0x4300u) c13++;
          }
          if (c5) atomicAdd(&cnts[0], c5);
          if (c11) atomicAdd(&cnts[1], c11);
          if (c13) atomicAdd(&cnts[2], c13);
          if ((((const unsigned short*)ab1)[t] & 0x7F80u) >= 0x4300u) atomicAdd(&cnts[3], 1);
          if ((((const unsigned short*)cb1)[t] & 0x7F80u) >= 0x4300u) atomicAdd(&cnts[4], 1);
          if ((((const unsigned short*)cb2)[t] & 0x7F80u) >= 0x4300u) atomicAdd(&cnts[5], 1);
          if ((((const unsigned short*)cw3)[t] & 0x7F80u) >= 0x4300u) atomicAdd(&cnts[6], 1);
        }
        // pooled reduce: device-scope atomic reads (bypass stale per-XCD L2)
        {
          const int col = t & 127;
          float v = 0.f;
          if (t < 128) {
#pragma unroll
            for (int sl = 0; sl < 16; ++sl)
              v += atomicAdd(&psumP[((long)b * 16 + sl) * 128 + col], 0.0f);
            v *= (1.0f / 10000.0f);
          } else {
#pragma unroll
            for (int sl = 0; sl < 16; ++sl)
              v = fmaxf(v, atomicAdd(&pmaxP[((long)b * 16 + sl) * 128 + col], 0.0f));
          }
          plfF[t] = v;
          plfQ[t] = bf2f(f2bf(v));
        }
        __syncthreads();
        const int Fa1 = cnts[0] > 256, Fc1 = cnts[1] > 256, Fc2 = cnts[2] > 256;
        const int Fab = cnts[3] > 32, Fb1 = cnts[4] > 32;
        const int Fb2 = cnts[5] > 32, Fc3 = cnts[6] > 32;

        // pact[col=t] = ab1[t] + plfQ . aw1[128:384, t]  (k-major, coalesced)
        {
          float p0 = 0.f, p1 = 0.f, p2 = 0.f, p3 = 0.f;
#pragma unroll 4
          for (int k = 0; k < 256; k += 4) {
            p0 += plfQ[k]     * gld(aw1, (long)(128 + k) * 256 + t, Fa1);
            p1 += plfQ[k + 1] * gld(aw1, (long)(129 + k) * 256 + t, Fa1);
            p2 += plfQ[k + 2] * gld(aw1, (long)(130 + k) * 256 + t, Fa1);
            p3 += plfQ[k + 3] * gld(aw1, (long)(131 + k) * 256 + t, Fa1);
          }
          pact[b * 256 + t] = gld(ab1, t, Fab) + ((p0 + p1) + (p2 + p3));
        }
        // critic layer 1 (raw f32 plf, original cw1)
        {
          float p0 = 0.f, p1 = 0.f, p2 = 0.f, p3 = 0.f;
#pragma unroll 4
          for (int k = 0; k < 256; k += 4) {
            p0 += plfF[k]     * gld(cw1, (long)(k)     * 256 + t, Fc1);
            p1 += plfF[k + 1] * gld(cw1, (long)(k + 1) * 256 + t, Fc1);
            p2 += plfF[k + 2] * gld(cw1, (long)(k + 2) * 256 + t, Fc1);
            p3 += plfF[k + 3] * gld(cw1, (long)(k + 3) * 256 + t, Fc1);
          }
          c1s[t] = fast_tanh(gld(cb1, t, Fb1) + ((p0 + p1) + (p2 + p3)));
        }
        __syncthreads();
        // critic layer 2 + head -> vws[b]
        {
          float p0 = 0.f, p1 = 0.f, p2 = 0.f, p3 = 0.f;
#pragma unroll 4
          for (int k = 0; k < 256; k += 4) {
            p0 += c1s[k]     * gld(cw2, (long)(k)     * 256 + t, Fc2);
            p1 += c1s[k + 1] * gld(cw2, (long)(k + 1) * 256 + t, Fc2);
            p2 += c1s[k + 2] * gld(cw2, (long)(k + 2) * 256 + t, Fc2);
            p3 += c1s[k + 3] * gld(cw2, (long)(k + 3) * 256 + t, Fc2);
          }
          float a2 = fast_tanh(gld(cb2, t, Fb2) + ((p0 + p1) + (p2 + p3)));
          float p = a2 * gld(cw3, t, Fc3);
          for (int o = 32; o; o >>= 1) p += __shfl_xor(p, o);
          if (lane == 0) redt[wv] = p;
          __syncthreads();
          if (t == 0) {
            int Fb3 = ((((const unsigned short*)cb3)[0] & 0x7F80u) >= 0x4300u) ? 1 : 0;
            vws[b] = redt[0] + redt[1] + redt[2] + redt[3] + gld(cb3, 0, Fb3);
          }
        }
      }
    } else {
      // ================= actorA role: h1c -> cf -> cfw =================
      unsigned short* h1c = pool;           // [32][72]
      const int idx = j - 1024;
      const int b = idx / 7;
      const int cb = idx % 7;
      const int cbase = cb * 29;

      if (t < 128) b2f[t] = gld(b2, t, F4);

      {
        int r = t & 31;
        int ci = cbase + r;
        if (ci > NCAND - 1) ci = NCAND - 1;
        long cidx = (long)b * NCAND + ci;
        int nd = C64 ? cand[2 * cidx] : cand[cidx];
        long xo = ((long)b * NN + nd) * 3;
        float x0 = gld(x, xo, F0), x1 = gld(x, xo + 1, F0), x2 = gld(x, xo + 2, F0);
        int kg = t >> 5;
#pragma unroll
        for (int i = 0; i < 8; ++i) {
          int k = kg * 8 + i;
          float v = x0 * gld(w1, k, F1) + x1 * gld(w1, 64 + k, F1) +
                    x2 * gld(w1, 128 + k, F1) + gld(b1, k, F2);
          h1c[r * 72 + k] = f2bf(fmaxf(v, 0.f));
        }
      }
      __syncthreads();

      {
        short8 af[2][2];
#pragma unroll
        for (int mt = 0; mt < 2; ++mt)
#pragma unroll
          for (int ks = 0; ks < 2; ++ks)
            af[mt][ks] = *(const short8*)(h1c + (mt * 16 + (lane & 15)) * 72 + ((lane >> 4) * 8) + ks * 32);
#pragma unroll
        for (int nl = 0; nl < 2; ++nl) {
          int col = wv * 32 + nl * 16 + (lane & 15);
          short8 bf0, bf1;
#pragma unroll
          for (int jj = 0; jj < 8; ++jj) {
            int k = (lane >> 4) * 8 + jj;
            bf0[jj] = (short)f2bf(gld(w2, (long)k * 128 + col, Fw2));
            bf1[jj] = (short)f2bf(gld(w2, (long)(k + 32) * 128 + col, Fw2));
          }
          float bb = b2f[col];
#pragma unroll
          for (int mt = 0; mt < 2; ++mt) {
            f32x4 acc = {0.f, 0.f, 0.f, 0.f};
            acc = __builtin_amdgcn_mfma_f32_16x16x32_bf16(af[mt][0], bf0, acc, 0, 0, 0);
            acc = __builtin_amdgcn_mfma_f32_16x16x32_bf16(af[mt][1], bf1, acc, 0, 0, 0);
#pragma unroll
            for (int r = 0; r < 4; ++r) {
              int row = mt * 16 + ((lane >> 4) * 4) + r;
              cfw[(long)idx * 4096 + row * 128 + col] = f2bf(fmaxf(acc[r] + bb, 0.f));
            }
          }
        }
      }
    }
    return;
  }

  // ---- housekeeping roles ----
  if (t < 8) cnts[t] = 0;
  __syncthreads();

  if (j < 1856) {
    const unsigned short* pa = (const unsigned short*)aw1;
    const unsigned short* pb = (const unsigned short*)aw2;
    if ((pa[t] & 0x7F80u) >= 0x4300u) atomicAdd(&cnts[0], 1);
    if ((pb[t] & 0x7F80u) >= 0x4300u) atomicAdd(&cnts[1], 1);
    __syncthreads();
    const int Faw1 = cnts[0] > 32, Faw2 = cnts[1] > 32;
    int i = (j - 1472) * 256 + t;
    if (i < 256 * 384) { int n = i / 384, k = i % 384; aw1t[i] = f2bf(gld(aw1, k * 256 + n, Faw1)); }
    if (i < 256 * 256) {
      int n = i >> 8, k = i & 255;
      aw2t[i] = f2bf(gld(aw2, k * 256 + n, Faw2));
    }
  } else if (j < 1873) {
    const void* ptrs[17] = {x, w1, b1, w2, b2, aw1, ab1, aw2, ab2, aw3, ab3,
                            cw1, cb1, cw2, cb2, cw3, cb3};
    const int sizes[17] = {1920000, 192, 64, 8192, 128, 98304, 256, 65536, 256,
                           256, 1, 65536, 256, 65536, 256, 256, 1};
    int a = j - 1856;
    const unsigned short* p = (const unsigned short*)ptrs[a];
    int K = min(sizes[a], 2048);
    int c = 0;
    for (int i = t; i < K; i += 256)
      if ((p[i] & 0x7F80u) >= 0x4300u) c++;
    if (c) atomicAdd(&cnts[0], c);
    __syncthreads();
    if (t == 0) F[a] = (cnts[0] > (K >> 3)) ? 1 : 0;
  } else if (j == 1873) {
    int flo = 0, fhi = 0, fgt = 0;
    for (int i = t; i < 3216; i += 256) {
      unsigned int w = mask_w[i];
      if ((w & 0xFFFFu) == 0x3F80u) flo = 1;
      if ((w >> 16) == 0x3F80u) fhi = 1;
      if (w > 1u) fgt = 1;
    }
    if (flo) cnts[0] = 1;
    if (fhi) cnts[1] = 1;
    if (fgt) cnts[2] = 1;
    __syncthreads();
    if (t == 0) F[17] = cnts[0] ? 2 : (cnts[1] ? 3 : (cnts[2] ? 1 : 0));
  } else {
    int co = 0;
    for (int i = t; i < 1024; i += 256)
      if ((i & 1) && cand_w[i] != 0u) co = 1;
    if (co) cnts[0] = 1;
    if (t < 64) scnt[t] = 0;
    __syncthreads();
    if (t == 0) F[18] = cnts[0] ? 0 : 1;
  }
}

// ---------------------------------------------------------------------------
// actorB: EXACT R0 body (best measured config, <40.4us) -- 448 blocks,
// layer-1 K=128 with pact bias from global, layers 2-3, masked softmax tail.
// Only addition: the amLast block also copies vws[b] (critic value computed
// by mega's tail) to out with the F-derived OF format.
// ---------------------------------------------------------------------------
__global__ __launch_bounds__(256)
void actorB_kernel(const unsigned short* __restrict__ cfw,
                   const void* __restrict__ ab2,
                   const void* __restrict__ aw3, const void* __restrict__ ab3,
                   const void* __restrict__ mask,
                   const int* __restrict__ F,
                   const float* __restrict__ pact,
                   const float* __restrict__ vws,
                   const unsigned short* __restrict__ aw1t,
                   const unsigned short* __restrict__ aw2t,
                   float* __restrict__ scores, int* __restrict__ scnt,
                   void* __restrict__ out) {
  __shared__ __align__(16) unsigned short a1s[32 * 264];
  __shared__ __align__(16) unsigned short a2s[32 * 264];
  __shared__ float pactS[256], ab2f[256];
  __shared__ float red[4];
  __shared__ int amLast;

  const int t = threadIdx.x;
  const int b = blockIdx.x / 7;
  const int cb = blockIdx.x % 7;
  const int cbase = cb * 29;
  const int cntc = min(29, NCAND - cbase);
  const int lane = t & 63;
  const int wv = t >> 6;
  const int F8 = F[8], F9 = F[9], F10 = F[10];

  pactS[t] = pact[b * 256 + t];
  ab2f[t] = gld(ab2, t, F8);

  // actor layer 1 (candidate part): [32 x 128] @ [128 x 256] + pact
  {
    f32x4 acc[2][4];
#pragma unroll
    for (int mt = 0; mt < 2; ++mt)
#pragma unroll
      for (int nt = 0; nt < 4; ++nt) acc[mt][nt] = (f32x4){0.f, 0.f, 0.f, 0.f};
    const unsigned short* cfb = cfw + (long)blockIdx.x * 4096;
#pragma unroll
    for (int ks = 0; ks < 4; ++ks) {
      short8 af0 = *(const short8*)(cfb + (lane & 15) * 128 + ks * 32 + ((lane >> 4) * 8));
      short8 af1 = *(const short8*)(cfb + (16 + (lane & 15)) * 128 + ks * 32 + ((lane >> 4) * 8));
#pragma unroll
      for (int nt = 0; nt < 4; ++nt) {
        int col = wv * 64 + nt * 16 + (lane & 15);
        short8 bfr = *(const short8*)(aw1t + col * 384 + ks * 32 + ((lane >> 4) * 8));
        acc[0][nt] = __builtin_amdgcn_mfma_f32_16x16x32_bf16(af0, bfr, acc[0][nt], 0, 0, 0);
        acc[1][nt] = __builtin_amdgcn_mfma_f32_16x16x32_bf16(af1, bfr, acc[1][nt], 0, 0, 0);
      }
    }
    __syncthreads();
#pragma unroll
    for (int mt = 0; mt < 2; ++mt)
#pragma unroll
      for (int nt = 0; nt < 4; ++nt) {
        int col = wv * 64 + nt * 16 + (lane & 15);
        float bb = pactS[col];
#pragma unroll
        for (int r = 0; r < 4; ++r) {
          int row = mt * 16 + ((lane >> 4) * 4) + r;
          a1s[row * 264 + col] = f2bf(fast_tanh(acc[mt][nt][r] + bb));
        }
      }
  }
  __syncthreads();

  // actor layer 2: [32 x 256] @ [256 x 256]
  {
    f32x4 acc[2][4];
#pragma unroll
    for (int mt = 0; mt < 2; ++mt)
#pragma unroll
      for (int nt = 0; nt < 4; ++nt) acc[mt][nt] = (f32x4){0.f, 0.f, 0.f, 0.f};
    for (int ks = 0; ks < 8; ++ks) {
      short8 af0 = *(const short8*)(a1s + (lane & 15) * 264 + ks * 32 + ((lane >> 4) * 8));
      short8 af1 = *(const short8*)(a1s + (16 + (lane & 15)) * 264 + ks * 32 + ((lane >> 4) * 8));
#pragma unroll
      for (int nt = 0; nt < 4; ++nt) {
        int col = wv * 64 + nt * 16 + (lane & 15);
        short8 bfr = *(const short8*)(aw2t + col * 256 + ks * 32 + ((lane >> 4) * 8));
        acc[0][nt] = __builtin_amdgcn_mfma_f32_16x16x32_bf16(af0, bfr, acc[0][nt], 0, 0, 0);
        acc[1][nt] = __builtin_amdgcn_mfma_f32_16x16x32_bf16(af1, bfr, acc[1][nt], 0, 0, 0);
      }
    }
#pragma unroll
    for (int mt = 0; mt < 2; ++mt)
#pragma unroll
      for (int nt = 0; nt < 4; ++nt) {
        int col = wv * 64 + nt * 16 + (lane & 15);
        float bb = ab2f[col];
#pragma unroll
        for (int r = 0; r < 4; ++r) {
          int row = mt * 16 + ((lane >> 4) * 4) + r;
          a2s[row * 264 + col] = f2bf(fast_tanh(acc[mt][nt][r] + bb));
        }
      }
  }
  __syncthreads();

  // layer 3: per-row dot-256 with a_w3 -> scores (device-scope atomicExch)
  {
    int row = t >> 3, seg = t & 7;
    float p = 0.f;
#pragma unroll 8
    for (int i = 0; i < 32; ++i) {
      int k = seg * 32 + i;
      p += bf2f(a2s[row * 264 + k]) * gld(aw3, k, F9);
    }
    p += __shfl_xor(p, 1);
    p += __shfl_xor(p, 2);
    p += __shfl_xor(p, 4);
    if (seg == 0 && row < cntc)
      atomicExch(&scores[b * 256 + cbase + row], p + gld(ab3, 0, F10));
  }
  __syncthreads();

  if (t == 0) {
    __threadfence();
    amLast = (atomicAdd(&scnt[b], 1) == 6);
  }
  __syncthreads();
  if (!amLast) return;

  // ---- masked softmax tail (last cand-block of this batch) ----
  const int MM = F[17];
  const int OF = (F[0] + F[1] + F[3] + F[5] + F[7] + F[9] + F[11] + F[13] + F[15]) >= 5;
  float sraw = 0.f, sv = -1e30f;
  bool valid = false;
  if (t < NCAND) {
    sraw = atomicAdd(&scores[b * 256 + t], 0.0f);   // coherent read
    long idx = (long)b * NCAND + t;
    if (MM == 0)      valid = ((const int*)mask)[idx] != 0;
    else if (MM == 1) valid = ((const unsigned char*)mask)[idx] != 0;
    else if (MM == 2) valid = ((const unsigned short*)mask)[idx] != 0;
    else              valid = ((const unsigned int*)mask)[idx] != 0;
    if (valid) sv = sraw;
  }
  float m = sv;
  for (int o = 32; o; o >>= 1) m = fmaxf(m, __shfl_xor(m, o));
  if (lane == 0) red[wv] = m;
  __syncthreads();
  m = fmaxf(fmaxf(red[0], red[1]), fmaxf(red[2], red[3]));
  __syncthreads();
  float e = valid ? __expf(sraw - m) : 0.f;
  if (!(e == e)) e = 0.f;  // scrub
  float ss = e;
  for (int o = 32; o; o >>= 1) ss += __shfl_xor(ss, o);
  if (lane == 0) red[wv] = ss;
  __syncthreads();
  float tot = red[0] + red[1] + red[2] + red[3];
  tot = fmaxf(tot, 1e-30f);
  if (t < NCAND) {
    float pv = e / tot;
    if (!(pv == pv)) pv = 0.f;  // scrub
    if (OF) ((float*)out)[b * NCAND + t] = pv;
    else ((unsigned short*)out)[b * NCAND + t] = f2bf(pv);
  }
  if (t == 0) {
    float v = vws[b];
    if (!(v == v)) v = 0.f;  // scrub
    if (OF) ((float*)out)[NB * NCAND + b] = v;
    else ((unsigned short*)out)[NB * NCAND + b] = f2bf(v);
  }
}

// ---------------------------------------------------------------------------
extern "C" void kernel_launch(void* const* d_in, const int* in_sizes, int n_in,
                              void* d_out, int out_size, void* d_ws, size_t ws_size,
                              hipStream_t stream) {
  const void* x = d_in[0];
  const int* cand = (const int*)d_in[1];
  const void* mask = d_in[2];
  const void* fe_w1 = d_in[3];
  const void* fe_b1 = d_in[4];
  const void* fe_w2 = d_in[5];
  const void* fe_b2 = d_in[6];
  const void* a_w1 = d_in[7];
  const void* a_b1 = d_in[8];
  const void* a_w2 = d_in[9];
  const void* a_b2 = d_in[10];
  const void* a_w3 = d_in[11];
  const void* a_b3 = d_in[12];
  const void* c_w1 = d_in[13];
  const void* c_b1 = d_in[14];
  const void* c_w2 = d_in[15];
  const void* c_b2 = d_in[16];
  const void* c_w3 = d_in[17];
  const void* c_b3 = d_in[18];

  char* ws = (char*)d_ws;
  int* fpcnt = (int*)(ws);                                // 64 ints (memset 0)
  float* vws = (float*)(ws + 1024);                       // 64 f32
  float* scores = (float*)(ws + 65536);                   // 64*256 f32
  unsigned short* aw1t = (unsigned short*)(ws + 147456);  // 256*384 bf16
  unsigned short* aw2t = (unsigned short*)(ws + 344064);  // 256*256 bf16
  int* F = (int*)(ws + 475136);                           // 20 ints
  float* pact = (float*)(ws + 737408);                    // 64*256 f32
  unsigned short* cfw = (unsigned short*)(ws + 802944);   // 448*4096 bf16
  int* scnt = (int*)(ws + 4472960);                       // 64 ints
  float* psumP = (float*)(ws + 4473216);                  // 64*16*128 f32
  float* pmaxP = (float*)(ws + 4997504);                  // 64*16*128 f32 (ends 5521792)

  hipMemsetAsync(fpcnt, 0, 256, stream);   // zero finisher counters (capturable)

  mega_kernel<<<1875, 256, 0, stream>>>(x, cand, fe_w1, fe_b1, fe_w2, fe_b2,
                                        a_w1, a_b1, a_w2, a_b2, a_w3, a_b3,
                                        c_w1, c_b1, c_w2, c_b2, c_w3, c_b3,
                                        (const unsigned int*)mask,
                                        (const unsigned int*)cand, F, scnt, fpcnt,
                                        psumP, pmaxP, pact, vws, cfw, aw1t, aw2t);
  actorB_kernel<<<448, 256, 0, stream>>>(cfw, a_b2, a_w3, a_b3, mask, F,
                                         pact, vws, aw1t, aw2t,
                                         scores, scnt, (void*)d_out);
}

// Round 5
// 157.565 us; speedup vs baseline: 1.3930x; 1.3930x over previous
//
#include <hip/hip_runtime.h>

#define NN 10000
#define NCAND 201
#define NB 64

typedef __attribute__((ext_vector_type(8))) short short8;
typedef __attribute__((ext_vector_type(4))) float f32x4;

__device__ __forceinline__ float bf2f(unsigned short u) {
  return __uint_as_float(((unsigned int)u) << 16);
}
__device__ __forceinline__ unsigned short f2bf(float f) {
  unsigned int u = __float_as_uint(f);
  u += 0x7FFFu + ((u >> 16) & 1u);   // RNE
  return (unsigned short)(u >> 16);
}
__device__ __forceinline__ float fast_tanh(float x) {
  return 1.0f - 2.0f / (__expf(2.0f * x) + 1.0f);
}
// generic load: flag=1 -> float32 array, flag=0 -> bf16 array
__device__ __forceinline__ float gld(const void* p, long i, int f) {
  return f ? ((const float*)p)[i] : bf2f(((const unsigned short*)p)[i]);
}

// ---------------------------------------------------------------------------
// R20: full revert to the R0 three-kernel structure (measured best, 156.8us).
// Fusion ledger (all within-harness measured):
//   R16 critic+pp as actorB roles, full-unroll dots  -> VGPR 196 cliff, +7us
//   R17 k-major scalar dots, unroll-8                -> 256-VMEM serial chain, +10us
//   R18 pact folded into layer-1 MFMA (K=384)        -> per-block pooled sweep, +13us
//   R19 pact/critic as mega feat_pool tail           -> serial appendix, mega +55us
// Conclusion: the pooled sweep + 256-k matvecs are ~10+us of SERIAL LATENCY
// wherever placed; only a dedicated parallel kernel (128 blocks paying it
// CONCURRENTLY) hides it. Only change vs R0: pp_critic's pooled sweep is
// float4-staged through LDS (1 latency round instead of 16; bit-identical
// reduction order).
// ---------------------------------------------------------------------------
__global__ __launch_bounds__(256, 4)
void mega_kernel(const void* __restrict__ x, const int* __restrict__ cand,
                 const void* w1, const void* b1, const void* w2, const void* b2,
                 const void* aw1, const void* ab1, const void* aw2, const void* ab2,
                 const void* aw3, const void* ab3,
                 const void* cw1, const void* cb1, const void* cw2, const void* cb2,
                 const void* cw3, const void* cb3,
                 const unsigned int* mask_w, const unsigned int* cand_w,
                 int* F, int* scnt,
                 float* __restrict__ psumP, float* __restrict__ pmaxP,
                 unsigned short* __restrict__ cfw,
                 unsigned short* __restrict__ aw1t, unsigned short* __restrict__ aw2t,
                 unsigned short* __restrict__ cw1t, unsigned short* __restrict__ cw2t) {
  __shared__ __align__(16) unsigned short pool[128 * 72];  // 18432 B overlay
  __shared__ float w1f[3 * 64];
  __shared__ float b1f[64];
  __shared__ float b2f[128];
  __shared__ int cnts[8];

  const int t = threadIdx.x;
  const int j = blockIdx.x;
  const int lane = t & 63;
  const int wv = t >> 6;

  if (j < 1472) {
    // ---- shared self-detect for fp/actorA roles: x,w1,b1,b2,w2,cand ----
    if (t < 8) cnts[t] = 0;
    __syncthreads();
    {
      if ((((const unsigned short*)x)[t] & 0x7F80u) >= 0x4300u) atomicAdd(&cnts[0], 1);
      if (t < 192 && (((const unsigned short*)w1)[t] & 0x7F80u) >= 0x4300u) atomicAdd(&cnts[1], 1);
      if (t < 64 && (((const unsigned short*)b1)[t] & 0x7F80u) >= 0x4300u) atomicAdd(&cnts[2], 1);
      if (t < 128 && (((const unsigned short*)b2)[t] & 0x7F80u) >= 0x4300u) atomicAdd(&cnts[3], 1);
      if ((((const unsigned short*)w2)[t] & 0x7F80u) >= 0x4300u) atomicAdd(&cnts[4], 1);
      int co = 0;
#pragma unroll
      for (int q = 0; q < 4; ++q) {
        int i = t * 4 + q;
        if ((i & 1) && cand_w[i] != 0u) co = 1;
      }
      if (co) atomicAdd(&cnts[5], 1);
    }
    __syncthreads();
    const int F0 = cnts[0] > 32, F1 = cnts[1] > 24, F2 = cnts[2] > 8;
    const int F4 = cnts[3] > 16, Fw2 = cnts[4] > 32, C64 = cnts[5] == 0;

    if (j < 1024) {
      // ================= feat_pool role =================
      unsigned short* h1s = pool;  // [128][72]
      const int b = j >> 4;
      const int s = j & 15;

      if (t < 192) w1f[t] = gld(w1, t, F1);
      if (t < 64) b1f[t] = gld(b1, t, F2);
      if (t < 128) b2f[t] = gld(b2, t, F4);

      // B fragments gathered from fe_w2 [k][n] (strided scalar, once/block)
      short8 bfr[2][2];
#pragma unroll
      for (int nl = 0; nl < 2; ++nl)
#pragma unroll
        for (int ks = 0; ks < 2; ++ks) {
          int col = wv * 32 + nl * 16 + (lane & 15);
          short8 v;
#pragma unroll
          for (int jj = 0; jj < 8; ++jj) {
            int k = (lane >> 4) * 8 + ks * 32 + jj;
            v[jj] = (short)f2bf(gld(w2, (long)k * 128 + col, Fw2));
          }
          bfr[nl][ks] = v;
        }
      __syncthreads();

      float csum[2] = {0.f, 0.f};
      float cmax[2] = {0.f, 0.f};
      const int m = t & 127;
      const int kg = t >> 7;

      float x0 = 0.f, x1 = 0.f, x2 = 0.f;
      if (s < 79) {
        int nb = s * 128;
        if (m < min(128, NN - nb)) {
          long xo = ((long)b * NN + nb + m) * 3;
          x0 = gld(x, xo, F0); x1 = gld(x, xo + 1, F0); x2 = gld(x, xo + 2, F0);
        }
      }

      for (int c = s; c < 79; c += 16) {
        int nb = c * 128;
        int cnt = (nb + 128 <= NN) ? 128 : (NN - nb);
        const bool full = (cnt == 128);  // uniform across block
        if (full) {
#pragma unroll
          for (int blk = 0; blk < 4; ++blk) {
            short8 v;
#pragma unroll
            for (int i = 0; i < 8; ++i) {
              int k = kg * 32 + blk * 8 + i;
              float vv = x0 * w1f[k] + x1 * w1f[64 + k] + x2 * w1f[128 + k] + b1f[k];
              v[i] = (short)f2bf(fmaxf(vv, 0.f));
            }
            *(short8*)(h1s + m * 72 + kg * 32 + blk * 8) = v;
          }
        } else if (m < cnt) {
#pragma unroll
          for (int blk = 0; blk < 4; ++blk) {
            short8 v;
#pragma unroll
            for (int i = 0; i < 8; ++i) {
              int k = kg * 32 + blk * 8 + i;
              float vv = x0 * w1f[k] + x1 * w1f[64 + k] + x2 * w1f[128 + k] + b1f[k];
              v[i] = (short)f2bf(fmaxf(vv, 0.f));
            }
            *(short8*)(h1s + m * 72 + kg * 32 + blk * 8) = v;
          }
        }
        {
          int cn = c + 16;
          float nx0 = 0.f, nx1 = 0.f, nx2 = 0.f;
          if (cn < 79) {
            int nbn = cn * 128;
            if (m < min(128, NN - nbn)) {
              long xo = ((long)b * NN + nbn + m) * 3;
              nx0 = gld(x, xo, F0); nx1 = gld(x, xo + 1, F0); nx2 = gld(x, xo + 2, F0);
            }
          }
          __syncthreads();
          x0 = nx0; x1 = nx1; x2 = nx2;
        }
        if (full) {
          // unchecked epilogue (all rows valid)
#pragma unroll
          for (int mt = 0; mt < 8; ++mt) {
            const unsigned short* ap = h1s + (mt * 16 + (lane & 15)) * 72 + ((lane >> 4) * 8);
            short8 af0 = *(const short8*)(ap);
            short8 af1 = *(const short8*)(ap + 32);
#pragma unroll
            for (int nl = 0; nl < 2; ++nl) {
              f32x4 acc = {0.f, 0.f, 0.f, 0.f};
              acc = __builtin_amdgcn_mfma_f32_16x16x32_bf16(af0, bfr[nl][0], acc, 0, 0, 0);
              acc = __builtin_amdgcn_mfma_f32_16x16x32_bf16(af1, bfr[nl][1], acc, 0, 0, 0);
              int col = wv * 32 + nl * 16 + (lane & 15);
              float bb = b2f[col];
#pragma unroll
              for (int r = 0; r < 4; ++r) {
                float v = fmaxf(acc[r] + bb, 0.f);
                csum[nl] += v;
                cmax[nl] = fmaxf(cmax[nl], v);
              }
            }
          }
        } else {
#pragma unroll
          for (int mt = 0; mt < 8; ++mt) {
            const unsigned short* ap = h1s + (mt * 16 + (lane & 15)) * 72 + ((lane >> 4) * 8);
            short8 af0 = *(const short8*)(ap);
            short8 af1 = *(const short8*)(ap + 32);
#pragma unroll
            for (int nl = 0; nl < 2; ++nl) {
              f32x4 acc = {0.f, 0.f, 0.f, 0.f};
              acc = __builtin_amdgcn_mfma_f32_16x16x32_bf16(af0, bfr[nl][0], acc, 0, 0, 0);
              acc = __builtin_amdgcn_mfma_f32_16x16x32_bf16(af1, bfr[nl][1], acc, 0, 0, 0);
              int col = wv * 32 + nl * 16 + (lane & 15);
              float bb = b2f[col];
#pragma unroll
              for (int r = 0; r < 4; ++r) {
                int row = mt * 16 + ((lane >> 4) * 4) + r;
                if (row < cnt) {
                  float v = fmaxf(acc[r] + bb, 0.f);
                  csum[nl] += v;
                  cmax[nl] = fmaxf(cmax[nl], v);
                }
              }
            }
          }
        }
        __syncthreads();
      }
#pragma unroll
      for (int nl = 0; nl < 2; ++nl) {
        csum[nl] += __shfl_xor(csum[nl], 16);
        csum[nl] += __shfl_xor(csum[nl], 32);
        cmax[nl] = fmaxf(cmax[nl], __shfl_xor(cmax[nl], 16));
        cmax[nl] = fmaxf(cmax[nl], __shfl_xor(cmax[nl], 32));
      }
      if (lane < 16) {
#pragma unroll
        for (int nl = 0; nl < 2; ++nl) {
          int col = wv * 32 + nl * 16 + lane;
          psumP[((long)b * 16 + s) * 128 + col] = csum[nl];   // plain stores
          pmaxP[((long)b * 16 + s) * 128 + col] = cmax[nl];
        }
      }
    } else {
      // ================= actorA role: h1c -> cf -> cfw =================
      unsigned short* h1c = pool;           // [32][72]
      const int idx = j - 1024;
      const int b = idx / 7;
      const int cb = idx % 7;
      const int cbase = cb * 29;

      if (t < 128) b2f[t] = gld(b2, t, F4);

      {
        int r = t & 31;
        int ci = cbase + r;
        if (ci > NCAND - 1) ci = NCAND - 1;
        long cidx = (long)b * NCAND + ci;
        int nd = C64 ? cand[2 * cidx] : cand[cidx];
        long xo = ((long)b * NN + nd) * 3;
        float x0 = gld(x, xo, F0), x1 = gld(x, xo + 1, F0), x2 = gld(x, xo + 2, F0);
        int kg = t >> 5;
#pragma unroll
        for (int i = 0; i < 8; ++i) {
          int k = kg * 8 + i;
          float v = x0 * gld(w1, k, F1) + x1 * gld(w1, 64 + k, F1) +
                    x2 * gld(w1, 128 + k, F1) + gld(b1, k, F2);
          h1c[r * 72 + k] = f2bf(fmaxf(v, 0.f));
        }
      }
      __syncthreads();

      {
        short8 af[2][2];
#pragma unroll
        for (int mt = 0; mt < 2; ++mt)
#pragma unroll
          for (int ks = 0; ks < 2; ++ks)
            af[mt][ks] = *(const short8*)(h1c + (mt * 16 + (lane & 15)) * 72 + ((lane >> 4) * 8) + ks * 32);
#pragma unroll
        for (int nl = 0; nl < 2; ++nl) {
          int col = wv * 32 + nl * 16 + (lane & 15);
          short8 bf0, bf1;
#pragma unroll
          for (int jj = 0; jj < 8; ++jj) {
            int k = (lane >> 4) * 8 + jj;
            bf0[jj] = (short)f2bf(gld(w2, (long)k * 128 + col, Fw2));
            bf1[jj] = (short)f2bf(gld(w2, (long)(k + 32) * 128 + col, Fw2));
          }
          float bb = b2f[col];
#pragma unroll
          for (int mt = 0; mt < 2; ++mt) {
            f32x4 acc = {0.f, 0.f, 0.f, 0.f};
            acc = __builtin_amdgcn_mfma_f32_16x16x32_bf16(af[mt][0], bf0, acc, 0, 0, 0);
            acc = __builtin_amdgcn_mfma_f32_16x16x32_bf16(af[mt][1], bf1, acc, 0, 0, 0);
#pragma unroll
            for (int r = 0; r < 4; ++r) {
              int row = mt * 16 + ((lane >> 4) * 4) + r;
              cfw[(long)idx * 4096 + row * 128 + col] = f2bf(fmaxf(acc[r] + bb, 0.f));
            }
          }
        }
      }
    }
    return;
  }

  // ---- housekeeping roles ----
  if (t < 8) cnts[t] = 0;
  __syncthreads();

  if (j < 1856) {
    const unsigned short* pa = (const unsigned short*)aw1;
    const unsigned short* pb = (const unsigned short*)aw2;
    const unsigned short* pc = (const unsigned short*)cw1;
    const unsigned short* pd = (const unsigned short*)cw2;
    if ((pa[t] & 0x7F80u) >= 0x4300u) atomicAdd(&cnts[0], 1);
    if ((pb[t] & 0x7F80u) >= 0x4300u) atomicAdd(&cnts[1], 1);
    if ((pc[t] & 0x7F80u) >= 0x4300u) atomicAdd(&cnts[2], 1);
    if ((pd[t] & 0x7F80u) >= 0x4300u) atomicAdd(&cnts[3], 1);
    __syncthreads();
    const int Faw1 = cnts[0] > 32, Faw2 = cnts[1] > 32;
    const int Fcw1 = cnts[2] > 32, Fcw2 = cnts[3] > 32;
    int i = (j - 1472) * 256 + t;
    if (i < 256 * 384) { int n = i / 384, k = i % 384; aw1t[i] = f2bf(gld(aw1, k * 256 + n, Faw1)); }
    if (i < 256 * 256) {
      int n = i >> 8, k = i & 255;
      aw2t[i] = f2bf(gld(aw2, k * 256 + n, Faw2));
      cw1t[i] = f2bf(gld(cw1, k * 256 + n, Fcw1));
      cw2t[i] = f2bf(gld(cw2, k * 256 + n, Fcw2));
    }
  } else if (j < 1873) {
    const void* ptrs[17] = {x, w1, b1, w2, b2, aw1, ab1, aw2, ab2, aw3, ab3,
                            cw1, cb1, cw2, cb2, cw3, cb3};
    const int sizes[17] = {1920000, 192, 64, 8192, 128, 98304, 256, 65536, 256,
                           256, 1, 65536, 256, 65536, 256, 256, 1};
    int a = j - 1856;
    const unsigned short* p = (const unsigned short*)ptrs[a];
    int K = min(sizes[a], 2048);
    int c = 0;
    for (int i = t; i < K; i += 256)
      if ((p[i] & 0x7F80u) >= 0x4300u) c++;
    if (c) atomicAdd(&cnts[0], c);
    __syncthreads();
    if (t == 0) F[a] = (cnts[0] > (K >> 3)) ? 1 : 0;
  } else if (j == 1873) {
    int flo = 0, fhi = 0, fgt = 0;
    for (int i = t; i < 3216; i += 256) {
      unsigned int w = mask_w[i];
      if ((w & 0xFFFFu) == 0x3F80u) flo = 1;
      if ((w >> 16) == 0x3F80u) fhi = 1;
      if (w > 1u) fgt = 1;
    }
    if (flo) cnts[0] = 1;
    if (fhi) cnts[1] = 1;
    if (fgt) cnts[2] = 1;
    __syncthreads();
    if (t == 0) F[17] = cnts[0] ? 2 : (cnts[1] ? 3 : (cnts[2] ? 1 : 0));
  } else {
    int co = 0;
    for (int i = t; i < 1024; i += 256)
      if ((i & 1) && cand_w[i] != 0u) co = 1;
    if (co) cnts[0] = 1;
    if (t < 64) scnt[t] = 0;
    __syncthreads();
    if (t == 0) F[18] = cnts[0] ? 0 : 1;
  }
}

// ---------------------------------------------------------------------------
// blocks 0..63: pooled projection -> pact; blocks 64..127: critic -> v
// R20: pooled sweep float4-staged through LDS (each thread: 4 independent
// float4 loads = ONE latency round, vs 16 serial dependent loads), then the
// per-col slice reduction runs from LDS in the SAME sl order (bit-identical).
// ---------------------------------------------------------------------------
__global__ __launch_bounds__(256)
void pp_critic_kernel(const float* __restrict__ psumP, const float* __restrict__ pmaxP,
                      const unsigned short* __restrict__ aw1t,
                      const void* __restrict__ ab1,
                      const unsigned short* __restrict__ cw1t,
                      const unsigned short* __restrict__ cw2t,
                      const void* __restrict__ cb1, const void* __restrict__ cb2,
                      const void* __restrict__ cw3, const void* __restrict__ cb3,
                      const int* __restrict__ F,
                      float* __restrict__ pact, void* __restrict__ out) {
  __shared__ float plf[256];
  __shared__ float c1f[256];
  __shared__ float red[4];
  __shared__ __align__(16) float ssl[2048];  // 16 slices x 128 cols (8 KB)
  __shared__ __align__(16) float msl[2048];  // 16 slices x 128 cols (8 KB)
  const int t = threadIdx.x;
  const int b = blockIdx.x & 63;
  const int lane = t & 63, wv = t >> 6;

  // stage all pooling partials: 2+2 float4 per thread, one latency round
  {
    const float4* ps = (const float4*)(psumP + (long)b * 2048);
    const float4* pm = (const float4*)(pmaxP + (long)b * 2048);
    float4 s0 = ps[t * 2], s1 = ps[t * 2 + 1];
    float4 m0 = pm[t * 2], m1 = pm[t * 2 + 1];
    ((float4*)ssl)[t * 2] = s0;
    ((float4*)ssl)[t * 2 + 1] = s1;
    ((float4*)msl)[t * 2] = m0;
    ((float4*)msl)[t * 2 + 1] = m1;
  }
  __syncthreads();

  // per-col reduce from LDS, same ascending-sl order as R0 (bit-identical)
  float ssum = 0.f, smax = 0.f;
  if (t < 128) {
#pragma unroll
    for (int sl = 0; sl < 16; ++sl) ssum += ssl[sl * 128 + t];
  } else {
    const int c = t - 128;
#pragma unroll
    for (int sl = 0; sl < 16; ++sl) smax = fmaxf(smax, msl[sl * 128 + c]);
  }

  if (blockIdx.x < 64) {
    const int F6 = F[6];
    if (t < 128) plf[t] = bf2f(f2bf(ssum * (1.0f / 10000.0f)));  // match actor bf16 quant
    else plf[t] = bf2f(f2bf(smax));
    __syncthreads();
    float a = gld(ab1, t, F6);
    const unsigned short* row = aw1t + t * 384 + 128;
#pragma unroll
    for (int k8 = 0; k8 < 32; ++k8) {
      short8 w = *(const short8*)(row + k8 * 8);
#pragma unroll
      for (int j = 0; j < 8; ++j)
        a += plf[k8 * 8 + j] * bf2f((unsigned short)w[j]);
    }
    pact[b * 256 + t] = a;
  } else {
    const int OF = (F[0] + F[1] + F[3] + F[5] + F[7] + F[9] + F[11] + F[13] + F[15]) >= 5;
    const int F12 = F[12], F14 = F[14], F15 = F[15], F16 = F[16];
    if (t < 128) plf[t] = ssum * (1.0f / 10000.0f);
    else plf[t] = smax;
    __syncthreads();
    {
      float a = gld(cb1, t, F12);
      const unsigned short* row = cw1t + t * 256;
#pragma unroll
      for (int k8 = 0; k8 < 32; ++k8) {
        short8 w = *(const short8*)(row + k8 * 8);
#pragma unroll
        for (int j = 0; j < 8; ++j)
          a += plf[k8 * 8 + j] * bf2f((unsigned short)w[j]);
      }
      c1f[t] = fast_tanh(a);
    }
    __syncthreads();
    {
      float a2 = gld(cb2, t, F14);
      const unsigned short* row = cw2t + t * 256;
#pragma unroll
      for (int k8 = 0; k8 < 32; ++k8) {
        short8 w = *(const short8*)(row + k8 * 8);
#pragma unroll
        for (int j = 0; j < 8; ++j)
          a2 += c1f[k8 * 8 + j] * bf2f((unsigned short)w[j]);
      }
      a2 = fast_tanh(a2);
      float p = a2 * gld(cw3, t, F15);
      for (int o = 32; o; o >>= 1) p += __shfl_xor(p, o);
      __syncthreads();
      if (lane == 0) red[wv] = p;
      __syncthreads();
      if (t == 0) {
        float v = red[0] + red[1] + red[2] + red[3] + gld(cb3, 0, F16);
        if (!(v == v)) v = 0.f;  // scrub
        if (OF) ((float*)out)[NB * NCAND + b] = v;
        else ((unsigned short*)out)[NB * NCAND + b] = f2bf(v);
      }
    }
  }
}

// ---------------------------------------------------------------------------
// actorB: layers 1-3 from cfw + pact -> scores; the LAST cand-block of each
// batch (per-batch counter) runs the masked softmax. scores via device-scope
// atomicExch; tail reads via atomicAdd(p,0) -- coherent across XCDs (G16).
// ---------------------------------------------------------------------------
__global__ __launch_bounds__(256)
void actorB_kernel(const unsigned short* __restrict__ cfw,
                   const void* __restrict__ ab2,
                   const void* __restrict__ aw3, const void* __restrict__ ab3,
                   const void* __restrict__ mask,
                   const int* __restrict__ F,
                   const float* __restrict__ pact,
                   const unsigned short* __restrict__ aw1t,
                   const unsigned short* __restrict__ aw2t,
                   float* __restrict__ scores, int* __restrict__ scnt,
                   void* __restrict__ out) {
  __shared__ __align__(16) unsigned short a1s[32 * 264];
  __shared__ __align__(16) unsigned short a2s[32 * 264];
  __shared__ float pactS[256], ab2f[256];
  __shared__ float red[4];
  __shared__ int amLast;

  const int t = threadIdx.x;
  const int b = blockIdx.x / 7;
  const int cb = blockIdx.x % 7;
  const int cbase = cb * 29;
  const int cntc = min(29, NCAND - cbase);
  const int lane = t & 63;
  const int wv = t >> 6;
  const int F8 = F[8], F9 = F[9], F10 = F[10];

  pactS[t] = pact[b * 256 + t];
  ab2f[t] = gld(ab2, t, F8);

  // actor layer 1 (candidate part): [32 x 128] @ [128 x 256] + pact
  {
    f32x4 acc[2][4];
#pragma unroll
    for (int mt = 0; mt < 2; ++mt)
#pragma unroll
      for (int nt = 0; nt < 4; ++nt) acc[mt][nt] = (f32x4){0.f, 0.f, 0.f, 0.f};
    const unsigned short* cfb = cfw + (long)blockIdx.x * 4096;
#pragma unroll
    for (int ks = 0; ks < 4; ++ks) {
      short8 af0 = *(const short8*)(cfb + (lane & 15) * 128 + ks * 32 + ((lane >> 4) * 8));
      short8 af1 = *(const short8*)(cfb + (16 + (lane & 15)) * 128 + ks * 32 + ((lane >> 4) * 8));
#pragma unroll
      for (int nt = 0; nt < 4; ++nt) {
        int col = wv * 64 + nt * 16 + (lane & 15);
        short8 bfr = *(const short8*)(aw1t + col * 384 + ks * 32 + ((lane >> 4) * 8));
        acc[0][nt] = __builtin_amdgcn_mfma_f32_16x16x32_bf16(af0, bfr, acc[0][nt], 0, 0, 0);
        acc[1][nt] = __builtin_amdgcn_mfma_f32_16x16x32_bf16(af1, bfr, acc[1][nt], 0, 0, 0);
      }
    }
    __syncthreads();
#pragma unroll
    for (int mt = 0; mt < 2; ++mt)
#pragma unroll
      for (int nt = 0; nt < 4; ++nt) {
        int col = wv * 64 + nt * 16 + (lane & 15);
        float bb = pactS[col];
#pragma unroll
        for (int r = 0; r < 4; ++r) {
          int row = mt * 16 + ((lane >> 4) * 4) + r;
          a1s[row * 264 + col] = f2bf(fast_tanh(acc[mt][nt][r] + bb));
        }
      }
  }
  __syncthreads();

  // actor layer 2: [32 x 256] @ [256 x 256]
  {
    f32x4 acc[2][4];
#pragma unroll
    for (int mt = 0; mt < 2; ++mt)
#pragma unroll
      for (int nt = 0; nt < 4; ++nt) acc[mt][nt] = (f32x4){0.f, 0.f, 0.f, 0.f};
    for (int ks = 0; ks < 8; ++ks) {
      short8 af0 = *(const short8*)(a1s + (lane & 15) * 264 + ks * 32 + ((lane >> 4) * 8));
      short8 af1 = *(const short8*)(a1s + (16 + (lane & 15)) * 264 + ks * 32 + ((lane >> 4) * 8));
#pragma unroll
      for (int nt = 0; nt < 4; ++nt) {
        int col = wv * 64 + nt * 16 + (lane & 15);
        short8 bfr = *(const short8*)(aw2t + col * 256 + ks * 32 + ((lane >> 4) * 8));
        acc[0][nt] = __builtin_amdgcn_mfma_f32_16x16x32_bf16(af0, bfr, acc[0][nt], 0, 0, 0);
        acc[1][nt] = __builtin_amdgcn_mfma_f32_16x16x32_bf16(af1, bfr, acc[1][nt], 0, 0, 0);
      }
    }
#pragma unroll
    for (int mt = 0; mt < 2; ++mt)
#pragma unroll
      for (int nt = 0; nt < 4; ++nt) {
        int col = wv * 64 + nt * 16 + (lane & 15);
        float bb = ab2f[col];
#pragma unroll
        for (int r = 0; r < 4; ++r) {
          int row = mt * 16 + ((lane >> 4) * 4) + r;
          a2s[row * 264 + col] = f2bf(fast_tanh(acc[mt][nt][r] + bb));
        }
      }
  }
  __syncthreads();

  // layer 3: per-row dot-256 with a_w3 -> scores (device-scope atomicExch)
  {
    int row = t >> 3, seg = t & 7;
    float p = 0.f;
#pragma unroll 8
    for (int i = 0; i < 32; ++i) {
      int k = seg * 32 + i;
      p += bf2f(a2s[row * 264 + k]) * gld(aw3, k, F9);
    }
    p += __shfl_xor(p, 1);
    p += __shfl_xor(p, 2);
    p += __shfl_xor(p, 4);
    if (seg == 0 && row < cntc)
      atomicExch(&scores[b * 256 + cbase + row], p + gld(ab3, 0, F10));
  }
  __syncthreads();

  if (t == 0) {
    __threadfence();
    amLast = (atomicAdd(&scnt[b], 1) == 6);
  }
  __syncthreads();
  if (!amLast) return;

  // ---- masked softmax tail (last cand-block of this batch) ----
  const int MM = F[17];
  const int OF = (F[0] + F[1] + F[3] + F[5] + F[7] + F[9] + F[11] + F[13] + F[15]) >= 5;
  float sraw = 0.f, sv = -1e30f;
  bool valid = false;
  if (t < NCAND) {
    sraw = atomicAdd(&scores[b * 256 + t], 0.0f);   // coherent read
    long idx = (long)b * NCAND + t;
    if (MM == 0)      valid = ((const int*)mask)[idx] != 0;
    else if (MM == 1) valid = ((const unsigned char*)mask)[idx] != 0;
    else if (MM == 2) valid = ((const unsigned short*)mask)[idx] != 0;
    else              valid = ((const unsigned int*)mask)[idx] != 0;
    if (valid) sv = sraw;
  }
  float m = sv;
  for (int o = 32; o; o >>= 1) m = fmaxf(m, __shfl_xor(m, o));
  if (lane == 0) red[wv] = m;
  __syncthreads();
  m = fmaxf(fmaxf(red[0], red[1]), fmaxf(red[2], red[3]));
  __syncthreads();
  float e = valid ? __expf(sraw - m) : 0.f;
  if (!(e == e)) e = 0.f;  // scrub
  float ss = e;
  for (int o = 32; o; o >>= 1) ss += __shfl_xor(ss, o);
  if (lane == 0) red[wv] = ss;
  __syncthreads();
  float tot = red[0] + red[1] + red[2] + red[3];
  tot = fmaxf(tot, 1e-30f);
  if (t < NCAND) {
    float pv = e / tot;
    if (!(pv == pv)) pv = 0.f;  // scrub
    if (OF) ((float*)out)[b * NCAND + t] = pv;
    else ((unsigned short*)out)[b * NCAND + t] = f2bf(pv);
  }
}

// ---------------------------------------------------------------------------
extern "C" void kernel_launch(void* const* d_in, const int* in_sizes, int n_in,
                              void* d_out, int out_size, void* d_ws, size_t ws_size,
                              hipStream_t stream) {
  const void* x = d_in[0];
  const int* cand = (const int*)d_in[1];
  const void* mask = d_in[2];
  const void* fe_w1 = d_in[3];
  const void* fe_b1 = d_in[4];
  const void* fe_w2 = d_in[5];
  const void* fe_b2 = d_in[6];
  const void* a_w1 = d_in[7];
  const void* a_b1 = d_in[8];
  const void* a_w2 = d_in[9];
  const void* a_b2 = d_in[10];
  const void* a_w3 = d_in[11];
  const void* a_b3 = d_in[12];
  const void* c_w1 = d_in[13];
  const void* c_b1 = d_in[14];
  const void* c_w2 = d_in[15];
  const void* c_b2 = d_in[16];
  const void* c_w3 = d_in[17];
  const void* c_b3 = d_in[18];

  char* ws = (char*)d_ws;
  float* scores = (float*)(ws + 65536);                   // 64*256 f32
  unsigned short* aw1t = (unsigned short*)(ws + 147456);  // 256*384 bf16
  unsigned short* aw2t = (unsigned short*)(ws + 344064);  // 256*256 bf16
  int* F = (int*)(ws + 475136);                           // 20 ints
  unsigned short* cw1t = (unsigned short*)(ws + 475264);  // 256*256 bf16
  unsigned short* cw2t = (unsigned short*)(ws + 606336);  // 256*256 bf16
  float* pact = (float*)(ws + 737408);                    // 64*256 f32
  unsigned short* cfw = (unsigned short*)(ws + 802944);   // 448*4096 bf16
  int* scnt = (int*)(ws + 4472960);                       // 64 ints
  float* psumP = (float*)(ws + 4473216);                  // 64*16*128 f32
  float* pmaxP = (float*)(ws + 4997504);                  // 64*16*128 f32 (ends 5521792)

  mega_kernel<<<1875, 256, 0, stream>>>(x, cand, fe_w1, fe_b1, fe_w2, fe_b2,
                                        a_w1, a_b1, a_w2, a_b2, a_w3, a_b3,
                                        c_w1, c_b1, c_w2, c_b2, c_w3, c_b3,
                                        (const unsigned int*)mask,
                                        (const unsigned int*)cand, F, scnt,
                                        psumP, pmaxP, cfw, aw1t, aw2t, cw1t, cw2t);
  pp_critic_kernel<<<128, 256, 0, stream>>>(psumP, pmaxP, aw1t, a_b1,
                                            cw1t, cw2t, c_b1, c_b2, c_w3, c_b3,
                                            F, pact, (void*)d_out);
  actorB_kernel<<<448, 256, 0, stream>>>(cfw, a_b2, a_w3, a_b3, mask, F, pact,
                                         aw1t, aw2t, scores, scnt, (void*)d_out);
}

// Round 6
// 155.798 us; speedup vs baseline: 1.4088x; 1.0113x over previous
//
#include <hip/hip_runtime.h>

#define NN 10000
#define NCAND 201
#define NB 64

typedef __attribute__((ext_vector_type(8))) short short8;
typedef __attribute__((ext_vector_type(4))) float f32x4;

__device__ __forceinline__ float bf2f(unsigned short u) {
  return __uint_as_float(((unsigned int)u) << 16);
}
__device__ __forceinline__ unsigned short f2bf(float f) {
  unsigned int u = __float_as_uint(f);
  u += 0x7FFFu + ((u >> 16) & 1u);   // RNE
  return (unsigned short)(u >> 16);
}
__device__ __forceinline__ float fast_tanh(float x) {
  return 1.0f - 2.0f / (__expf(2.0f * x) + 1.0f);
}
// generic load: flag=1 -> float32 array, flag=0 -> bf16 array
__device__ __forceinline__ float gld(const void* p, long i, int f) {
  return f ? ((const float*)p)[i] : bf2f(((const unsigned short*)p)[i]);
}

// ---------------------------------------------------------------------------
// R21: two-kernel structure. pp_critic's work moves into the actorB launch as
// single-producer roles (NOT per-block redundant -- the R16-R18 mistake):
//   cb==0 block of each batch: computes pact[b] once, publishes via
//     device-scope atomics + flag (mirrors the proven scores/scnt pattern).
//   cb==1 block: computes critic v[b], writes out directly.
//   other blocks: candidate-K MFMA first (no pact needed), then poll flag;
//     bounded spin + bit-identical local recompute fallback => correctness
//     does not depend on dispatch order (G16).
// Fusion ledger: R16 VGPR cliff / R17 serial k-major chain / R18 per-block
// pooled sweep / R19 serial tail -- all placed pooled work on a critical
// path ~7x or on an idle GPU. R21 places it ONCE, overlapped with MFMA.
// ---------------------------------------------------------------------------
__global__ __launch_bounds__(256, 4)
void mega_kernel(const void* __restrict__ x, const int* __restrict__ cand,
                 const void* w1, const void* b1, const void* w2, const void* b2,
                 const void* aw1, const void* ab1, const void* aw2, const void* ab2,
                 const void* aw3, const void* ab3,
                 const void* cw1, const void* cb1, const void* cw2, const void* cb2,
                 const void* cw3, const void* cb3,
                 const unsigned int* mask_w, const unsigned int* cand_w,
                 int* F, int* scnt, int* pflag,
                 float* __restrict__ psumP, float* __restrict__ pmaxP,
                 unsigned short* __restrict__ cfw,
                 unsigned short* __restrict__ aw1t, unsigned short* __restrict__ aw2t,
                 unsigned short* __restrict__ cw1t, unsigned short* __restrict__ cw2t) {
  __shared__ __align__(16) unsigned short pool[128 * 72];  // 18432 B overlay
  __shared__ float w1f[3 * 64];
  __shared__ float b1f[64];
  __shared__ float b2f[128];
  __shared__ int cnts[8];

  const int t = threadIdx.x;
  const int j = blockIdx.x;
  const int lane = t & 63;
  const int wv = t >> 6;

  if (j < 1472) {
    // ---- shared self-detect for fp/actorA roles: x,w1,b1,b2,w2,cand ----
    if (t < 8) cnts[t] = 0;
    __syncthreads();
    {
      if ((((const unsigned short*)x)[t] & 0x7F80u) >= 0x4300u) atomicAdd(&cnts[0], 1);
      if (t < 192 && (((const unsigned short*)w1)[t] & 0x7F80u) >= 0x4300u) atomicAdd(&cnts[1], 1);
      if (t < 64 && (((const unsigned short*)b1)[t] & 0x7F80u) >= 0x4300u) atomicAdd(&cnts[2], 1);
      if (t < 128 && (((const unsigned short*)b2)[t] & 0x7F80u) >= 0x4300u) atomicAdd(&cnts[3], 1);
      if ((((const unsigned short*)w2)[t] & 0x7F80u) >= 0x4300u) atomicAdd(&cnts[4], 1);
      int co = 0;
#pragma unroll
      for (int q = 0; q < 4; ++q) {
        int i = t * 4 + q;
        if ((i & 1) && cand_w[i] != 0u) co = 1;
      }
      if (co) atomicAdd(&cnts[5], 1);
    }
    __syncthreads();
    const int F0 = cnts[0] > 32, F1 = cnts[1] > 24, F2 = cnts[2] > 8;
    const int F4 = cnts[3] > 16, Fw2 = cnts[4] > 32, C64 = cnts[5] == 0;

    if (j < 1024) {
      // ================= feat_pool role =================
      unsigned short* h1s = pool;  // [128][72]
      const int b = j >> 4;
      const int s = j & 15;

      if (t < 192) w1f[t] = gld(w1, t, F1);
      if (t < 64) b1f[t] = gld(b1, t, F2);
      if (t < 128) b2f[t] = gld(b2, t, F4);

      // B fragments gathered from fe_w2 [k][n] (strided scalar, once/block)
      short8 bfr[2][2];
#pragma unroll
      for (int nl = 0; nl < 2; ++nl)
#pragma unroll
        for (int ks = 0; ks < 2; ++ks) {
          int col = wv * 32 + nl * 16 + (lane & 15);
          short8 v;
#pragma unroll
          for (int jj = 0; jj < 8; ++jj) {
            int k = (lane >> 4) * 8 + ks * 32 + jj;
            v[jj] = (short)f2bf(gld(w2, (long)k * 128 + col, Fw2));
          }
          bfr[nl][ks] = v;
        }
      __syncthreads();

      float csum[2] = {0.f, 0.f};
      float cmax[2] = {0.f, 0.f};
      const int m = t & 127;
      const int kg = t >> 7;

      float x0 = 0.f, x1 = 0.f, x2 = 0.f;
      if (s < 79) {
        int nb = s * 128;
        if (m < min(128, NN - nb)) {
          long xo = ((long)b * NN + nb + m) * 3;
          x0 = gld(x, xo, F0); x1 = gld(x, xo + 1, F0); x2 = gld(x, xo + 2, F0);
        }
      }

      for (int c = s; c < 79; c += 16) {
        int nb = c * 128;
        int cnt = (nb + 128 <= NN) ? 128 : (NN - nb);
        const bool full = (cnt == 128);  // uniform across block
        if (full) {
#pragma unroll
          for (int blk = 0; blk < 4; ++blk) {
            short8 v;
#pragma unroll
            for (int i = 0; i < 8; ++i) {
              int k = kg * 32 + blk * 8 + i;
              float vv = x0 * w1f[k] + x1 * w1f[64 + k] + x2 * w1f[128 + k] + b1f[k];
              v[i] = (short)f2bf(fmaxf(vv, 0.f));
            }
            *(short8*)(h1s + m * 72 + kg * 32 + blk * 8) = v;
          }
        } else if (m < cnt) {
#pragma unroll
          for (int blk = 0; blk < 4; ++blk) {
            short8 v;
#pragma unroll
            for (int i = 0; i < 8; ++i) {
              int k = kg * 32 + blk * 8 + i;
              float vv = x0 * w1f[k] + x1 * w1f[64 + k] + x2 * w1f[128 + k] + b1f[k];
              v[i] = (short)f2bf(fmaxf(vv, 0.f));
            }
            *(short8*)(h1s + m * 72 + kg * 32 + blk * 8) = v;
          }
        }
        {
          int cn = c + 16;
          float nx0 = 0.f, nx1 = 0.f, nx2 = 0.f;
          if (cn < 79) {
            int nbn = cn * 128;
            if (m < min(128, NN - nbn)) {
              long xo = ((long)b * NN + nbn + m) * 3;
              nx0 = gld(x, xo, F0); nx1 = gld(x, xo + 1, F0); nx2 = gld(x, xo + 2, F0);
            }
          }
          __syncthreads();
          x0 = nx0; x1 = nx1; x2 = nx2;
        }
        if (full) {
          // unchecked epilogue (all rows valid)
#pragma unroll
          for (int mt = 0; mt < 8; ++mt) {
            const unsigned short* ap = h1s + (mt * 16 + (lane & 15)) * 72 + ((lane >> 4) * 8);
            short8 af0 = *(const short8*)(ap);
            short8 af1 = *(const short8*)(ap + 32);
#pragma unroll
            for (int nl = 0; nl < 2; ++nl) {
              f32x4 acc = {0.f, 0.f, 0.f, 0.f};
              acc = __builtin_amdgcn_mfma_f32_16x16x32_bf16(af0, bfr[nl][0], acc, 0, 0, 0);
              acc = __builtin_amdgcn_mfma_f32_16x16x32_bf16(af1, bfr[nl][1], acc, 0, 0, 0);
              int col = wv * 32 + nl * 16 + (lane & 15);
              float bb = b2f[col];
#pragma unroll
              for (int r = 0; r < 4; ++r) {
                float v = fmaxf(acc[r] + bb, 0.f);
                csum[nl] += v;
                cmax[nl] = fmaxf(cmax[nl], v);
              }
            }
          }
        } else {
#pragma unroll
          for (int mt = 0; mt < 8; ++mt) {
            const unsigned short* ap = h1s + (mt * 16 + (lane & 15)) * 72 + ((lane >> 4) * 8);
            short8 af0 = *(const short8*)(ap);
            short8 af1 = *(const short8*)(ap + 32);
#pragma unroll
            for (int nl = 0; nl < 2; ++nl) {
              f32x4 acc = {0.f, 0.f, 0.f, 0.f};
              acc = __builtin_amdgcn_mfma_f32_16x16x32_bf16(af0, bfr[nl][0], acc, 0, 0, 0);
              acc = __builtin_amdgcn_mfma_f32_16x16x32_bf16(af1, bfr[nl][1], acc, 0, 0, 0);
              int col = wv * 32 + nl * 16 + (lane & 15);
              float bb = b2f[col];
#pragma unroll
              for (int r = 0; r < 4; ++r) {
                int row = mt * 16 + ((lane >> 4) * 4) + r;
                if (row < cnt) {
                  float v = fmaxf(acc[r] + bb, 0.f);
                  csum[nl] += v;
                  cmax[nl] = fmaxf(cmax[nl], v);
                }
              }
            }
          }
        }
        __syncthreads();
      }
#pragma unroll
      for (int nl = 0; nl < 2; ++nl) {
        csum[nl] += __shfl_xor(csum[nl], 16);
        csum[nl] += __shfl_xor(csum[nl], 32);
        cmax[nl] = fmaxf(cmax[nl], __shfl_xor(cmax[nl], 16));
        cmax[nl] = fmaxf(cmax[nl], __shfl_xor(cmax[nl], 32));
      }
      if (lane < 16) {
#pragma unroll
        for (int nl = 0; nl < 2; ++nl) {
          int col = wv * 32 + nl * 16 + lane;
          psumP[((long)b * 16 + s) * 128 + col] = csum[nl];   // plain stores
          pmaxP[((long)b * 16 + s) * 128 + col] = cmax[nl];
        }
      }
    } else {
      // ================= actorA role: h1c -> cf -> cfw =================
      unsigned short* h1c = pool;           // [32][72]
      const int idx = j - 1024;
      const int b = idx / 7;
      const int cb = idx % 7;
      const int cbase = cb * 29;

      if (t < 128) b2f[t] = gld(b2, t, F4);

      {
        int r = t & 31;
        int ci = cbase + r;
        if (ci > NCAND - 1) ci = NCAND - 1;
        long cidx = (long)b * NCAND + ci;
        int nd = C64 ? cand[2 * cidx] : cand[cidx];
        long xo = ((long)b * NN + nd) * 3;
        float x0 = gld(x, xo, F0), x1 = gld(x, xo + 1, F0), x2 = gld(x, xo + 2, F0);
        int kg = t >> 5;
#pragma unroll
        for (int i = 0; i < 8; ++i) {
          int k = kg * 8 + i;
          float v = x0 * gld(w1, k, F1) + x1 * gld(w1, 64 + k, F1) +
                    x2 * gld(w1, 128 + k, F1) + gld(b1, k, F2);
          h1c[r * 72 + k] = f2bf(fmaxf(v, 0.f));
        }
      }
      __syncthreads();

      {
        short8 af[2][2];
#pragma unroll
        for (int mt = 0; mt < 2; ++mt)
#pragma unroll
          for (int ks = 0; ks < 2; ++ks)
            af[mt][ks] = *(const short8*)(h1c + (mt * 16 + (lane & 15)) * 72 + ((lane >> 4) * 8) + ks * 32);
#pragma unroll
        for (int nl = 0; nl < 2; ++nl) {
          int col = wv * 32 + nl * 16 + (lane & 15);
          short8 bf0, bf1;
#pragma unroll
          for (int jj = 0; jj < 8; ++jj) {
            int k = (lane >> 4) * 8 + jj;
            bf0[jj] = (short)f2bf(gld(w2, (long)k * 128 + col, Fw2));
            bf1[jj] = (short)f2bf(gld(w2, (long)(k + 32) * 128 + col, Fw2));
          }
          float bb = b2f[col];
#pragma unroll
          for (int mt = 0; mt < 2; ++mt) {
            f32x4 acc = {0.f, 0.f, 0.f, 0.f};
            acc = __builtin_amdgcn_mfma_f32_16x16x32_bf16(af[mt][0], bf0, acc, 0, 0, 0);
            acc = __builtin_amdgcn_mfma_f32_16x16x32_bf16(af[mt][1], bf1, acc, 0, 0, 0);
#pragma unroll
            for (int r = 0; r < 4; ++r) {
              int row = mt * 16 + ((lane >> 4) * 4) + r;
              cfw[(long)idx * 4096 + row * 128 + col] = f2bf(fmaxf(acc[r] + bb, 0.f));
            }
          }
        }
      }
    }
    return;
  }

  // ---- housekeeping roles ----
  if (t < 8) cnts[t] = 0;
  __syncthreads();

  if (j < 1856) {
    const unsigned short* pa = (const unsigned short*)aw1;
    const unsigned short* pb = (const unsigned short*)aw2;
    const unsigned short* pc = (const unsigned short*)cw1;
    const unsigned short* pd = (const unsigned short*)cw2;
    if ((pa[t] & 0x7F80u) >= 0x4300u) atomicAdd(&cnts[0], 1);
    if ((pb[t] & 0x7F80u) >= 0x4300u) atomicAdd(&cnts[1], 1);
    if ((pc[t] & 0x7F80u) >= 0x4300u) atomicAdd(&cnts[2], 1);
    if ((pd[t] & 0x7F80u) >= 0x4300u) atomicAdd(&cnts[3], 1);
    __syncthreads();
    const int Faw1 = cnts[0] > 32, Faw2 = cnts[1] > 32;
    const int Fcw1 = cnts[2] > 32, Fcw2 = cnts[3] > 32;
    int i = (j - 1472) * 256 + t;
    if (i < 256 * 384) { int n = i / 384, k = i % 384; aw1t[i] = f2bf(gld(aw1, k * 256 + n, Faw1)); }
    if (i < 256 * 256) {
      int n = i >> 8, k = i & 255;
      aw2t[i] = f2bf(gld(aw2, k * 256 + n, Faw2));
      cw1t[i] = f2bf(gld(cw1, k * 256 + n, Fcw1));
      cw2t[i] = f2bf(gld(cw2, k * 256 + n, Fcw2));
    }
  } else if (j < 1873) {
    const void* ptrs[17] = {x, w1, b1, w2, b2, aw1, ab1, aw2, ab2, aw3, ab3,
                            cw1, cb1, cw2, cb2, cw3, cb3};
    const int sizes[17] = {1920000, 192, 64, 8192, 128, 98304, 256, 65536, 256,
                           256, 1, 65536, 256, 65536, 256, 256, 1};
    int a = j - 1856;
    const unsigned short* p = (const unsigned short*)ptrs[a];
    int K = min(sizes[a], 2048);
    int c = 0;
    for (int i = t; i < K; i += 256)
      if ((p[i] & 0x7F80u) >= 0x4300u) c++;
    if (c) atomicAdd(&cnts[0], c);
    __syncthreads();
    if (t == 0) F[a] = (cnts[0] > (K >> 3)) ? 1 : 0;
  } else if (j == 1873) {
    int flo = 0, fhi = 0, fgt = 0;
    for (int i = t; i < 3216; i += 256) {
      unsigned int w = mask_w[i];
      if ((w & 0xFFFFu) == 0x3F80u) flo = 1;
      if ((w >> 16) == 0x3F80u) fhi = 1;
      if (w > 1u) fgt = 1;
    }
    if (flo) cnts[0] = 1;
    if (fhi) cnts[1] = 1;
    if (fgt) cnts[2] = 1;
    __syncthreads();
    if (t == 0) F[17] = cnts[0] ? 2 : (cnts[1] ? 3 : (cnts[2] ? 1 : 0));
  } else {
    int co = 0;
    for (int i = t; i < 1024; i += 256)
      if ((i & 1) && cand_w[i] != 0u) co = 1;
    if (co) cnts[0] = 1;
    if (t < 64) scnt[t] = 0;
    if (t >= 64 && t < 128) pflag[t - 64] = 0;   // zero pact-ready flags
    __syncthreads();
    if (t == 0) F[18] = cnts[0] ? 0 : 1;
  }
}

// ---------------------------------------------------------------------------
// actorB (R21): 448 blocks, launch_bounds(256,4). Per batch b (7 blocks):
//   cb==0: compute plf+pact ONCE (bit-identical to old pp_critic), publish
//          via atomicExch + threadfence + pflag (proven scores pattern).
//   cb==1: compute critic v[b] -> out, then normal actor work.
//   all:   candidate-K MFMA first (pact not needed), then acquire pact
//          (cb==0 has it locally; others poll flag w/ bounded spin +
//          bit-identical local recompute fallback -> no scheduling dependence).
// LDS overlay: a1s/a2s double as f32 staging for the pooling partials
// (consumed before layer-1 epilogue writes them). Total LDS unchanged.
// ---------------------------------------------------------------------------
__global__ __launch_bounds__(256, 4)
void actorB_kernel(const unsigned short* __restrict__ cfw,
                   const void* __restrict__ ab1, const void* __restrict__ ab2,
                   const void* __restrict__ aw3, const void* __restrict__ ab3,
                   const void* __restrict__ mask,
                   const int* __restrict__ F,
                   const float* __restrict__ psumP, const float* __restrict__ pmaxP,
                   float* __restrict__ pact, int* __restrict__ pflag,
                   const unsigned short* __restrict__ aw1t,
                   const unsigned short* __restrict__ aw2t,
                   const unsigned short* __restrict__ cw1t,
                   const unsigned short* __restrict__ cw2t,
                   const void* __restrict__ cb1, const void* __restrict__ cb2,
                   const void* __restrict__ cw3, const void* __restrict__ cb3,
                   float* __restrict__ scores, int* __restrict__ scnt,
                   void* __restrict__ out) {
  __shared__ __align__(16) unsigned short a1s[32 * 264];   // 16896 B
  __shared__ __align__(16) unsigned short a2s[32 * 264];   // 16896 B
  __shared__ float pactS[256], ab2f[256];
  __shared__ float red[4];
  __shared__ int amLast;
  __shared__ int pready;

  const int t = threadIdx.x;
  const int b = blockIdx.x / 7;
  const int cb = blockIdx.x % 7;
  const int cbase = cb * 29;
  const int cntc = min(29, NCAND - cbase);
  const int lane = t & 63;
  const int wv = t >> 6;
  const int F8 = F[8], F9 = F[9], F10 = F[10];

  float* stgS = (float*)a1s;   // 2048 f32 staging (overlay, consumed early)
  float* stgM = (float*)a2s;

  if (cb == 0) {
    // ---- producer: plf (bf16-quant) + pact, published once ----
    const int F6 = F[6];
    {
      const float4* ps = (const float4*)(psumP + (long)b * 2048);
      const float4* pm = (const float4*)(pmaxP + (long)b * 2048);
      ((float4*)stgS)[t * 2] = ps[t * 2];
      ((float4*)stgS)[t * 2 + 1] = ps[t * 2 + 1];
      ((float4*)stgM)[t * 2] = pm[t * 2];
      ((float4*)stgM)[t * 2 + 1] = pm[t * 2 + 1];
    }
    __syncthreads();
    {
      float r = 0.f;
      if (t < 128) {
#pragma unroll
        for (int sl = 0; sl < 16; ++sl) r += stgS[sl * 128 + t];
        r = bf2f(f2bf(r * (1.0f / 10000.0f)));
      } else {
        const int c = t - 128;
#pragma unroll
        for (int sl = 0; sl < 16; ++sl) r = fmaxf(r, stgM[sl * 128 + c]);
        r = bf2f(f2bf(r));
      }
      pactS[t] = r;   // plfQ (temporary)
    }
    __syncthreads();
    float a = gld(ab1, t, F6);
    {
      const unsigned short* row = aw1t + t * 384 + 128;
#pragma unroll 4
      for (int k8 = 0; k8 < 32; ++k8) {
        short8 w = *(const short8*)(row + k8 * 8);
#pragma unroll
        for (int jj = 0; jj < 8; ++jj)
          a += pactS[k8 * 8 + jj] * bf2f((unsigned short)w[jj]);
      }
    }
    __syncthreads();           // all done reading plfQ
    pactS[t] = a;
    atomicExch(&pact[(long)b * 256 + t], a);   // device-coherent publish
    __syncthreads();
    if (t == 0) {
      __threadfence();
      atomicExch(&pflag[b], 1);
    }
  } else if (cb == 1) {
    // ---- critic role: v[b] -> out (plf unquantized, bit-identical) ----
    const int OF = (F[0] + F[1] + F[3] + F[5] + F[7] + F[9] + F[11] + F[13] + F[15]) >= 5;
    const int F12 = F[12], F14 = F[14], F15 = F[15], F16 = F[16];
    {
      const float4* ps = (const float4*)(psumP + (long)b * 2048);
      const float4* pm = (const float4*)(pmaxP + (long)b * 2048);
      ((float4*)stgS)[t * 2] = ps[t * 2];
      ((float4*)stgS)[t * 2 + 1] = ps[t * 2 + 1];
      ((float4*)stgM)[t * 2] = pm[t * 2];
      ((float4*)stgM)[t * 2 + 1] = pm[t * 2 + 1];
    }
    __syncthreads();
    {
      float r = 0.f;
      if (t < 128) {
#pragma unroll
        for (int sl = 0; sl < 16; ++sl) r += stgS[sl * 128 + t];
        r *= (1.0f / 10000.0f);
      } else {
        const int c = t - 128;
#pragma unroll
        for (int sl = 0; sl < 16; ++sl) r = fmaxf(r, stgM[sl * 128 + c]);
      }
      pactS[t] = r;   // plfF (temporary, unquantized)
    }
    __syncthreads();
    {
      float a = gld(cb1, t, F12);
      const unsigned short* row = cw1t + t * 256;
#pragma unroll 4
      for (int k8 = 0; k8 < 32; ++k8) {
        short8 w = *(const short8*)(row + k8 * 8);
#pragma unroll
        for (int jj = 0; jj < 8; ++jj)
          a += pactS[k8 * 8 + jj] * bf2f((unsigned short)w[jj]);
      }
      ab2f[t] = fast_tanh(a);   // c1 activations (ab2f reused, reloaded later)
    }
    __syncthreads();
    {
      float a2 = gld(cb2, t, F14);
      const unsigned short* row = cw2t + t * 256;
#pragma unroll 4
      for (int k8 = 0; k8 < 32; ++k8) {
        short8 w = *(const short8*)(row + k8 * 8);
#pragma unroll
        for (int jj = 0; jj < 8; ++jj)
          a2 += ab2f[k8 * 8 + jj] * bf2f((unsigned short)w[jj]);
      }
      a2 = fast_tanh(a2);
      float p = a2 * gld(cw3, t, F15);
      for (int o = 32; o; o >>= 1) p += __shfl_xor(p, o);
      if (lane == 0) red[wv] = p;
      __syncthreads();
      if (t == 0) {
        float v = red[0] + red[1] + red[2] + red[3] + gld(cb3, 0, F16);
        if (!(v == v)) v = 0.f;  // scrub
        if (OF) ((float*)out)[NB * NCAND + b] = v;
        else ((unsigned short*)out)[NB * NCAND + b] = f2bf(v);
      }
      __syncthreads();
    }
  }

  // ================= common actor path =================
  // actor layer 1 (candidate part): [32 x 128] @ [128 x 256] -- no pact yet
  f32x4 acc[2][4];
#pragma unroll
  for (int mt = 0; mt < 2; ++mt)
#pragma unroll
    for (int nt = 0; nt < 4; ++nt) acc[mt][nt] = (f32x4){0.f, 0.f, 0.f, 0.f};
  {
    const unsigned short* cfb = cfw + (long)blockIdx.x * 4096;
#pragma unroll
    for (int ks = 0; ks < 4; ++ks) {
      short8 af0 = *(const short8*)(cfb + (lane & 15) * 128 + ks * 32 + ((lane >> 4) * 8));
      short8 af1 = *(const short8*)(cfb + (16 + (lane & 15)) * 128 + ks * 32 + ((lane >> 4) * 8));
#pragma unroll
      for (int nt = 0; nt < 4; ++nt) {
        int col = wv * 64 + nt * 16 + (lane & 15);
        short8 bfr = *(const short8*)(aw1t + col * 384 + ks * 32 + ((lane >> 4) * 8));
        acc[0][nt] = __builtin_amdgcn_mfma_f32_16x16x32_bf16(af0, bfr, acc[0][nt], 0, 0, 0);
        acc[1][nt] = __builtin_amdgcn_mfma_f32_16x16x32_bf16(af1, bfr, acc[1][nt], 0, 0, 0);
      }
    }
  }

  // ---- acquire pact (cb==0 already has it in pactS) ----
  if (cb != 0) {
    if (t == 0) {
      int ok = 1, spins = 0;
      while (atomicAdd(&pflag[b], 0) == 0) {
        if (++spins > 100000) { ok = 0; break; }   // fallback: recompute locally
        __builtin_amdgcn_s_sleep(2);
      }
      pready = ok;
    }
    __syncthreads();
    if (pready) {
      pactS[t] = atomicAdd(&pact[(long)b * 256 + t], 0.0f);  // coherent read
    } else {
      // bit-identical local recompute (scheduling-independence fallback)
      const int F6 = F[6];
      {
        const float4* ps = (const float4*)(psumP + (long)b * 2048);
        const float4* pm = (const float4*)(pmaxP + (long)b * 2048);
        ((float4*)stgS)[t * 2] = ps[t * 2];
        ((float4*)stgS)[t * 2 + 1] = ps[t * 2 + 1];
        ((float4*)stgM)[t * 2] = pm[t * 2];
        ((float4*)stgM)[t * 2 + 1] = pm[t * 2 + 1];
      }
      __syncthreads();
      {
        float r = 0.f;
        if (t < 128) {
#pragma unroll
          for (int sl = 0; sl < 16; ++sl) r += stgS[sl * 128 + t];
          r = bf2f(f2bf(r * (1.0f / 10000.0f)));
        } else {
          const int c = t - 128;
#pragma unroll
          for (int sl = 0; sl < 16; ++sl) r = fmaxf(r, stgM[sl * 128 + c]);
          r = bf2f(f2bf(r));
        }
        ab2f[t] = r;   // plfQ temp (ab2f reloaded below)
      }
      __syncthreads();
      float a = gld(ab1, t, F6);
      {
        const unsigned short* row = aw1t + t * 384 + 128;
#pragma unroll 4
        for (int k8 = 0; k8 < 32; ++k8) {
          short8 w = *(const short8*)(row + k8 * 8);
#pragma unroll
          for (int jj = 0; jj < 8; ++jj)
            a += ab2f[k8 * 8 + jj] * bf2f((unsigned short)w[jj]);
        }
      }
      __syncthreads();
      pactS[t] = a;
    }
    __syncthreads();
  }

  ab2f[t] = gld(ab2, t, F8);
  __syncthreads();

  // layer-1 epilogue (a1s safe: staging overlay fully consumed above)
#pragma unroll
  for (int mt = 0; mt < 2; ++mt)
#pragma unroll
    for (int nt = 0; nt < 4; ++nt) {
      int col = wv * 64 + nt * 16 + (lane & 15);
      float bb = pactS[col];
#pragma unroll
      for (int r = 0; r < 4; ++r) {
        int row = mt * 16 + ((lane >> 4) * 4) + r;
        a1s[row * 264 + col] = f2bf(fast_tanh(acc[mt][nt][r] + bb));
      }
    }
  __syncthreads();

  // actor layer 2: [32 x 256] @ [256 x 256]
  {
    f32x4 acc2[2][4];
#pragma unroll
    for (int mt = 0; mt < 2; ++mt)
#pragma unroll
      for (int nt = 0; nt < 4; ++nt) acc2[mt][nt] = (f32x4){0.f, 0.f, 0.f, 0.f};
    for (int ks = 0; ks < 8; ++ks) {
      short8 af0 = *(const short8*)(a1s + (lane & 15) * 264 + ks * 32 + ((lane >> 4) * 8));
      short8 af1 = *(const short8*)(a1s + (16 + (lane & 15)) * 264 + ks * 32 + ((lane >> 4) * 8));
#pragma unroll
      for (int nt = 0; nt < 4; ++nt) {
        int col = wv * 64 + nt * 16 + (lane & 15);
        short8 bfr = *(const short8*)(aw2t + col * 256 + ks * 32 + ((lane >> 4) * 8));
        acc2[0][nt] = __builtin_amdgcn_mfma_f32_16x16x32_bf16(af0, bfr, acc2[0][nt], 0, 0, 0);
        acc2[1][nt] = __builtin_amdgcn_mfma_f32_16x16x32_bf16(af1, bfr, acc2[1][nt], 0, 0, 0);
      }
    }
#pragma unroll
    for (int mt = 0; mt < 2; ++mt)
#pragma unroll
      for (int nt = 0; nt < 4; ++nt) {
        int col = wv * 64 + nt * 16 + (lane & 15);
        float bb = ab2f[col];
#pragma unroll
        for (int r = 0; r < 4; ++r) {
          int row = mt * 16 + ((lane >> 4) * 4) + r;
          a2s[row * 264 + col] = f2bf(fast_tanh(acc2[mt][nt][r] + bb));
        }
      }
  }
  __syncthreads();

  // layer 3: per-row dot-256 with a_w3 -> scores (device-scope atomicExch)
  {
    int row = t >> 3, seg = t & 7;
    float p = 0.f;
#pragma unroll 8
    for (int i = 0; i < 32; ++i) {
      int k = seg * 32 + i;
      p += bf2f(a2s[row * 264 + k]) * gld(aw3, k, F9);
    }
    p += __shfl_xor(p, 1);
    p += __shfl_xor(p, 2);
    p += __shfl_xor(p, 4);
    if (seg == 0 && row < cntc)
      atomicExch(&scores[b * 256 + cbase + row], p + gld(ab3, 0, F10));
  }
  __syncthreads();

  if (t == 0) {
    __threadfence();
    amLast = (atomicAdd(&scnt[b], 1) == 6);
  }
  __syncthreads();
  if (!amLast) return;

  // ---- masked softmax tail (last cand-block of this batch) ----
  const int MM = F[17];
  const int OF = (F[0] + F[1] + F[3] + F[5] + F[7] + F[9] + F[11] + F[13] + F[15]) >= 5;
  float sraw = 0.f, sv = -1e30f;
  bool valid = false;
  if (t < NCAND) {
    sraw = atomicAdd(&scores[b * 256 + t], 0.0f);   // coherent read
    long idx = (long)b * NCAND + t;
    if (MM == 0)      valid = ((const int*)mask)[idx] != 0;
    else if (MM == 1) valid = ((const unsigned char*)mask)[idx] != 0;
    else if (MM == 2) valid = ((const unsigned short*)mask)[idx] != 0;
    else              valid = ((const unsigned int*)mask)[idx] != 0;
    if (valid) sv = sraw;
  }
  float m = sv;
  for (int o = 32; o; o >>= 1) m = fmaxf(m, __shfl_xor(m, o));
  if (lane == 0) red[wv] = m;
  __syncthreads();
  m = fmaxf(fmaxf(red[0], red[1]), fmaxf(red[2], red[3]));
  __syncthreads();
  float e = valid ? __expf(sraw - m) : 0.f;
  if (!(e == e)) e = 0.f;  // scrub
  float ss = e;
  for (int o = 32; o; o >>= 1) ss += __shfl_xor(ss, o);
  if (lane == 0) red[wv] = ss;
  __syncthreads();
  float tot = red[0] + red[1] + red[2] + red[3];
  tot = fmaxf(tot, 1e-30f);
  if (t < NCAND) {
    float pv = e / tot;
    if (!(pv == pv)) pv = 0.f;  // scrub
    if (OF) ((float*)out)[b * NCAND + t] = pv;
    else ((unsigned short*)out)[b * NCAND + t] = f2bf(pv);
  }
}

// ---------------------------------------------------------------------------
extern "C" void kernel_launch(void* const* d_in, const int* in_sizes, int n_in,
                              void* d_out, int out_size, void* d_ws, size_t ws_size,
                              hipStream_t stream) {
  const void* x = d_in[0];
  const int* cand = (const int*)d_in[1];
  const void* mask = d_in[2];
  const void* fe_w1 = d_in[3];
  const void* fe_b1 = d_in[4];
  const void* fe_w2 = d_in[5];
  const void* fe_b2 = d_in[6];
  const void* a_w1 = d_in[7];
  const void* a_b1 = d_in[8];
  const void* a_w2 = d_in[9];
  const void* a_b2 = d_in[10];
  const void* a_w3 = d_in[11];
  const void* a_b3 = d_in[12];
  const void* c_w1 = d_in[13];
  const void* c_b1 = d_in[14];
  const void* c_w2 = d_in[15];
  const void* c_b2 = d_in[16];
  const void* c_w3 = d_in[17];
  const void* c_b3 = d_in[18];

  char* ws = (char*)d_ws;
  int* pflag = (int*)(ws);                                // 64 ints (zeroed in mega)
  float* scores = (float*)(ws + 65536);                   // 64*256 f32
  unsigned short* aw1t = (unsigned short*)(ws + 147456);  // 256*384 bf16
  unsigned short* aw2t = (unsigned short*)(ws + 344064);  // 256*256 bf16
  int* F = (int*)(ws + 475136);                           // 20 ints
  unsigned short* cw1t = (unsigned short*)(ws + 475264);  // 256*256 bf16
  unsigned short* cw2t = (unsigned short*)(ws + 606336);  // 256*256 bf16
  float* pact = (float*)(ws + 737408);                    // 64*256 f32
  unsigned short* cfw = (unsigned short*)(ws + 802944);   // 448*4096 bf16
  int* scnt = (int*)(ws + 4472960);                       // 64 ints
  float* psumP = (float*)(ws + 4473216);                  // 64*16*128 f32
  float* pmaxP = (float*)(ws + 4997504);                  // 64*16*128 f32 (ends 5521792)

  mega_kernel<<<1875, 256, 0, stream>>>(x, cand, fe_w1, fe_b1, fe_w2, fe_b2,
                                        a_w1, a_b1, a_w2, a_b2, a_w3, a_b3,
                                        c_w1, c_b1, c_w2, c_b2, c_w3, c_b3,
                                        (const unsigned int*)mask,
                                        (const unsigned int*)cand, F, scnt, pflag,
                                        psumP, pmaxP, cfw, aw1t, aw2t, cw1t, cw2t);
  actorB_kernel<<<448, 256, 0, stream>>>(cfw, a_b1, a_b2, a_w3, a_b3, mask, F,
                                         psumP, pmaxP, pact, pflag,
                                         aw1t, aw2t, cw1t, cw2t,
                                         c_b1, c_b2, c_w3, c_b3,
                                         scores, scnt, (void*)d_out);
}